// Round 1
// baseline (613.657 us; speedup 1.0000x reference)
//
#include <hip/hip_runtime.h>
#include <math.h>

#define D_IN  512
#define D_HID 64
#define D_OUT 40

// ---------------------------------------------------------------------------
// GEMM1: h1[N,64] = x[N,512] @ W1[512,64] + b1
// W1 (128 KiB fp32) staged fully in LDS; 1 block/CU (LDS-limited), 16 waves.
// Each wave computes 8 nodes at a time: lane t owns output column t,
// one ds_read_b32 of W1[k][t] feeds 8 FMAs (one per node).
// ---------------------------------------------------------------------------
__global__ __launch_bounds__(1024)
void gemm1_kernel(const float* __restrict__ x, const float* __restrict__ W1,
                  const float* __restrict__ b1, float* __restrict__ h1, int N) {
    __shared__ float w1s[D_IN * D_HID];  // 131072 B
    {
        const float4* s4 = reinterpret_cast<const float4*>(W1);
        float4* d4 = reinterpret_cast<float4*>(w1s);
        for (int i = threadIdx.x; i < D_IN * D_HID / 4; i += blockDim.x)
            d4[i] = s4[i];
    }
    __syncthreads();

    const int lane = threadIdx.x & 63;
    const int wid  = threadIdx.x >> 6;
    const int gw   = blockIdx.x * (blockDim.x >> 6) + wid;
    const int nW   = (gridDim.x * blockDim.x) >> 6;
    const float bias = b1[lane];

    const int NPW = 8;  // nodes per wave-iteration; 50000 % 8 == 0
    for (int base = gw * NPW; base < N; base += nW * NPW) {
        float acc[NPW];
#pragma unroll
        for (int j = 0; j < NPW; ++j) acc[j] = 0.f;

        if (base + NPW <= N) {
            for (int k = 0; k < D_IN; k += 4) {
                float xr[NPW][4];
#pragma unroll
                for (int j = 0; j < NPW; ++j) {
                    float4 t = *reinterpret_cast<const float4*>(
                        x + (size_t)(base + j) * D_IN + k);
                    xr[j][0] = t.x; xr[j][1] = t.y; xr[j][2] = t.z; xr[j][3] = t.w;
                }
#pragma unroll
                for (int kk = 0; kk < 4; ++kk) {
                    const float wv = w1s[(k + kk) * D_HID + lane];
#pragma unroll
                    for (int j = 0; j < NPW; ++j)
                        acc[j] += xr[j][kk] * wv;
                }
            }
#pragma unroll
            for (int j = 0; j < NPW; ++j)
                h1[(size_t)(base + j) * D_HID + lane] = acc[j] + bias;
        } else {
            for (int j = 0; j < NPW && base + j < N; ++j) {
                float a = 0.f;
                for (int k = 0; k < D_IN; ++k)
                    a += x[(size_t)(base + j) * D_IN + k] * w1s[k * D_HID + lane];
                h1[(size_t)(base + j) * D_HID + lane] = a + bias;
            }
        }
    }
}

// ---------------------------------------------------------------------------
// Aggregate: agg[dst] += w * h[src]  (one wave per edge, lane = channel)
// ---------------------------------------------------------------------------
template <int D>
__global__ void aggregate_kernel(const float* __restrict__ h,
                                 const int* __restrict__ src,
                                 const int* __restrict__ dst,
                                 const float* __restrict__ wm,
                                 float* __restrict__ agg, int E) {
    const int lane = threadIdx.x & 63;
    const int gw   = (blockIdx.x * blockDim.x + threadIdx.x) >> 6;
    const int nW   = (gridDim.x * blockDim.x) >> 6;
    for (int e = gw; e < E; e += nW) {
        const int   s = src[e];
        const int   d = dst[e];
        const float w = wm[e];
        if (lane < D) {
            const float v = h[(size_t)s * D + lane];
            atomicAdd(agg + (size_t)d * D + lane, w * v);
        }
    }
}

// ---------------------------------------------------------------------------
// GEMM2: h2[N,40] = relu(agg1[N,64]) @ W2[64,40] + b2   (wave per node)
// ---------------------------------------------------------------------------
__global__ void gemm2_kernel(const float* __restrict__ agg1,
                             const float* __restrict__ W2,
                             const float* __restrict__ b2,
                             float* __restrict__ h2, int N) {
    __shared__ float w2s[D_HID * D_OUT];  // 10 KiB
    __shared__ float b2s[D_OUT];
    for (int i = threadIdx.x; i < D_HID * D_OUT; i += blockDim.x) w2s[i] = W2[i];
    if (threadIdx.x < D_OUT) b2s[threadIdx.x] = b2[threadIdx.x];
    __syncthreads();

    const int lane = threadIdx.x & 63;
    const int col  = (lane < D_OUT) ? lane : 0;  // lanes >=40 compute garbage, never write
    const int gw   = (blockIdx.x * blockDim.x + threadIdx.x) >> 6;
    const int nW   = (gridDim.x * blockDim.x) >> 6;

    for (int n = gw; n < N; n += nW) {
        float acc = b2s[col];
        const float* row = agg1 + (size_t)n * D_HID;
        for (int k = 0; k < D_HID; k += 4) {
            float4 a4 = *reinterpret_cast<const float4*>(row + k);
            const float a0 = fmaxf(a4.x, 0.f);
            const float a1 = fmaxf(a4.y, 0.f);
            const float a2 = fmaxf(a4.z, 0.f);
            const float a3 = fmaxf(a4.w, 0.f);
            acc += a0 * w2s[(k + 0) * D_OUT + col];
            acc += a1 * w2s[(k + 1) * D_OUT + col];
            acc += a2 * w2s[(k + 2) * D_OUT + col];
            acc += a3 * w2s[(k + 3) * D_OUT + col];
        }
        if (lane < D_OUT) h2[(size_t)n * D_OUT + lane] = acc;
    }
}

// ---------------------------------------------------------------------------
// log_softmax over 40 classes, in-place on d_out (wave per node)
// ---------------------------------------------------------------------------
__global__ void logsoftmax_kernel(float* __restrict__ io, int N) {
    const int lane = threadIdx.x & 63;
    const int gw   = (blockIdx.x * blockDim.x + threadIdx.x) >> 6;
    const int nW   = (gridDim.x * blockDim.x) >> 6;
    for (int n = gw; n < N; n += nW) {
        const float v = (lane < D_OUT) ? io[(size_t)n * D_OUT + lane] : -INFINITY;
        float m = v;
#pragma unroll
        for (int o = 32; o > 0; o >>= 1) m = fmaxf(m, __shfl_xor(m, o, 64));
        float s = (lane < D_OUT) ? __expf(v - m) : 0.f;
#pragma unroll
        for (int o = 32; o > 0; o >>= 1) s += __shfl_xor(s, o, 64);
        if (lane < D_OUT) io[(size_t)n * D_OUT + lane] = v - m - __logf(s);
    }
}

// ---------------------------------------------------------------------------
extern "C" void kernel_launch(void* const* d_in, const int* in_sizes, int n_in,
                              void* d_out, int out_size, void* d_ws, size_t ws_size,
                              hipStream_t stream) {
    const float* x   = (const float*)d_in[0];
    const int*   ei  = (const int*)d_in[1];
    const float* wm  = (const float*)d_in[2];
    const float* W1  = (const float*)d_in[3];
    const float* b1  = (const float*)d_in[4];
    const float* W2  = (const float*)d_in[5];
    const float* b2  = (const float*)d_in[6];

    const int N = in_sizes[0] / D_IN;   // 50000
    const int E = in_sizes[2];          // 800000
    const int* srcIdx = ei;             // edge_index[0]
    const int* dstIdx = ei + E;         // edge_index[1]

    float* h1   = (float*)d_ws;                    // N*64 floats
    float* agg1 = h1 + (size_t)N * D_HID;          // N*64 floats
    float* h2   = h1;                              // reuse: h1 dead after aggregate1
    float* out  = (float*)d_out;                   // agg2 accumulates here

    // zero the scatter-add destinations (harness poisons, graph replays reuse)
    hipMemsetAsync(agg1, 0, (size_t)N * D_HID * sizeof(float), stream);
    hipMemsetAsync(out,  0, (size_t)N * D_OUT * sizeof(float), stream);

    gemm1_kernel<<<256, 1024, 0, stream>>>(x, W1, b1, h1, N);
    aggregate_kernel<D_HID><<<2048, 256, 0, stream>>>(h1, srcIdx, dstIdx, wm, agg1, E);
    gemm2_kernel<<<2048, 256, 0, stream>>>(agg1, W2, b2, h2, N);
    aggregate_kernel<D_OUT><<<2048, 256, 0, stream>>>(h2, srcIdx, dstIdx, wm, out, E);
    logsoftmax_kernel<<<2048, 256, 0, stream>>>(out, N);
}

// Round 2
// 443.705 us; speedup vs baseline: 1.3830x; 1.3830x over previous
//
#include <hip/hip_runtime.h>
#include <math.h>

#define D_IN  512
#define D_HID 64
#define D_OUT 40

// ---------------------------------------------------------------------------
// GEMM1: h1[N,64] = x[N,512] @ W1[512,64] + b1
// Register-tiled fp32 GEMM. Block = 256 threads, tile BM=256 nodes x 64 cols,
// BK=32. x-tile stored TRANSPOSED in LDS (k-major) so the inner loop reads
// both operands with ds_read_b128. Per thread: 8 nodes x 8 cols = 64 accs.
// LDS = 33.3K (xsT, +4 pad) + 8K (W1 tile) -> 3 blocks/CU, 12 waves/CU.
// ---------------------------------------------------------------------------
#define BM 256
#define BK 32

__global__ __launch_bounds__(256)
void gemm1_kernel(const float* __restrict__ x, const float* __restrict__ W1,
                  const float* __restrict__ b1, float* __restrict__ h1, int N) {
    __shared__ float xsT[BK][BM + 4];   // [k][node], pad 4 keeps b128 align, 2-way reads
    __shared__ float ws[BK][D_HID];     // [k][col]

    const int t = threadIdx.x;
    const int nodeBase = blockIdx.x * BM;
    const int nb = t >> 3;              // 0..31 -> nodes nb*8 .. nb*8+7
    const int cb = t & 7;               // 0..7  -> cols  cb*8 .. cb*8+7
    const int kq = t & 7;               // staging: which float4 of the 32-k chunk

    float acc[8][8];
#pragma unroll
    for (int i = 0; i < 8; ++i)
#pragma unroll
        for (int j = 0; j < 8; ++j) acc[i][j] = 0.f;

    for (int k0 = 0; k0 < D_IN; k0 += BK) {
        // ---- stage x tile: 256 nodes x 32 k, coalesced (8 nodes x 128B per instr)
#pragma unroll
        for (int r = 0; r < 8; ++r) {
            const int node = r * 32 + (t >> 3);
            int gn = nodeBase + node;
            if (gn >= N) gn = N - 1;                  // clamp; tail stores are guarded
            const float4 v = *reinterpret_cast<const float4*>(
                x + (size_t)gn * D_IN + k0 + kq * 4);
            xsT[kq * 4 + 0][node] = v.x;
            xsT[kq * 4 + 1][node] = v.y;
            xsT[kq * 4 + 2][node] = v.z;
            xsT[kq * 4 + 3][node] = v.w;
        }
        // ---- stage W1 tile: rows k0..k0+31 are 2048 contiguous floats
        {
            const float4* wsrc = reinterpret_cast<const float4*>(W1 + (size_t)k0 * D_HID);
            float4* wdst = reinterpret_cast<float4*>(&ws[0][0]);
            wdst[t]       = wsrc[t];
            wdst[t + 256] = wsrc[t + 256];
        }
        __syncthreads();

#pragma unroll 4
        for (int k = 0; k < BK; ++k) {
            const float4 xa = *reinterpret_cast<const float4*>(&xsT[k][nb * 8]);
            const float4 xb = *reinterpret_cast<const float4*>(&xsT[k][nb * 8 + 4]);
            const float4 wa = *reinterpret_cast<const float4*>(&ws[k][cb * 8]);
            const float4 wb = *reinterpret_cast<const float4*>(&ws[k][cb * 8 + 4]);
            const float xv[8] = {xa.x, xa.y, xa.z, xa.w, xb.x, xb.y, xb.z, xb.w};
            const float wv[8] = {wa.x, wa.y, wa.z, wa.w, wb.x, wb.y, wb.z, wb.w};
#pragma unroll
            for (int i = 0; i < 8; ++i)
#pragma unroll
                for (int j = 0; j < 8; ++j)
                    acc[i][j] += xv[i] * wv[j];
        }
        __syncthreads();
    }

    float bb[8];
#pragma unroll
    for (int j = 0; j < 8; ++j) bb[j] = b1[cb * 8 + j];

#pragma unroll
    for (int i = 0; i < 8; ++i) {
        const int gn = nodeBase + nb * 8 + i;
        if (gn < N) {
            float4 o0 = {acc[i][0] + bb[0], acc[i][1] + bb[1],
                         acc[i][2] + bb[2], acc[i][3] + bb[3]};
            float4 o1 = {acc[i][4] + bb[4], acc[i][5] + bb[5],
                         acc[i][6] + bb[6], acc[i][7] + bb[7]};
            float4* dst = reinterpret_cast<float4*>(h1 + (size_t)gn * D_HID + cb * 8);
            dst[0] = o0;
            dst[1] = o1;
        }
    }
}

// ---------------------------------------------------------------------------
// Aggregate: agg[dst] += w * h[src]  (one wave per edge, lane = channel)
// ---------------------------------------------------------------------------
template <int D>
__global__ void aggregate_kernel(const float* __restrict__ h,
                                 const int* __restrict__ src,
                                 const int* __restrict__ dst,
                                 const float* __restrict__ wm,
                                 float* __restrict__ agg, int E) {
    const int lane = threadIdx.x & 63;
    const int gw   = (blockIdx.x * blockDim.x + threadIdx.x) >> 6;
    const int nW   = (gridDim.x * blockDim.x) >> 6;
    for (int e = gw; e < E; e += nW) {
        const int   s = src[e];
        const int   d = dst[e];
        const float w = wm[e];
        if (lane < D) {
            const float v = h[(size_t)s * D + lane];
            atomicAdd(agg + (size_t)d * D + lane, w * v);
        }
    }
}

// ---------------------------------------------------------------------------
// GEMM2: h2[N,40] = relu(agg1[N,64]) @ W2[64,40] + b2   (wave per node)
// ---------------------------------------------------------------------------
__global__ void gemm2_kernel(const float* __restrict__ agg1,
                             const float* __restrict__ W2,
                             const float* __restrict__ b2,
                             float* __restrict__ h2, int N) {
    __shared__ float w2s[D_HID * D_OUT];  // 10 KiB
    __shared__ float b2s[D_OUT];
    for (int i = threadIdx.x; i < D_HID * D_OUT; i += blockDim.x) w2s[i] = W2[i];
    if (threadIdx.x < D_OUT) b2s[threadIdx.x] = b2[threadIdx.x];
    __syncthreads();

    const int lane = threadIdx.x & 63;
    const int col  = (lane < D_OUT) ? lane : 0;
    const int gw   = (blockIdx.x * blockDim.x + threadIdx.x) >> 6;
    const int nW   = (gridDim.x * blockDim.x) >> 6;

    for (int n = gw; n < N; n += nW) {
        float acc = b2s[col];
        const float* row = agg1 + (size_t)n * D_HID;
        for (int k = 0; k < D_HID; k += 4) {
            float4 a4 = *reinterpret_cast<const float4*>(row + k);
            const float a0 = fmaxf(a4.x, 0.f);
            const float a1 = fmaxf(a4.y, 0.f);
            const float a2 = fmaxf(a4.z, 0.f);
            const float a3 = fmaxf(a4.w, 0.f);
            acc += a0 * w2s[(k + 0) * D_OUT + col];
            acc += a1 * w2s[(k + 1) * D_OUT + col];
            acc += a2 * w2s[(k + 2) * D_OUT + col];
            acc += a3 * w2s[(k + 3) * D_OUT + col];
        }
        if (lane < D_OUT) h2[(size_t)n * D_OUT + lane] = acc;
    }
}

// ---------------------------------------------------------------------------
// log_softmax over 40 classes, in-place on d_out (wave per node)
// ---------------------------------------------------------------------------
__global__ void logsoftmax_kernel(float* __restrict__ io, int N) {
    const int lane = threadIdx.x & 63;
    const int gw   = (blockIdx.x * blockDim.x + threadIdx.x) >> 6;
    const int nW   = (gridDim.x * blockDim.x) >> 6;
    for (int n = gw; n < N; n += nW) {
        const float v = (lane < D_OUT) ? io[(size_t)n * D_OUT + lane] : -INFINITY;
        float m = v;
#pragma unroll
        for (int o = 32; o > 0; o >>= 1) m = fmaxf(m, __shfl_xor(m, o, 64));
        float s = (lane < D_OUT) ? __expf(v - m) : 0.f;
#pragma unroll
        for (int o = 32; o > 0; o >>= 1) s += __shfl_xor(s, o, 64);
        if (lane < D_OUT) io[(size_t)n * D_OUT + lane] = v - m - __logf(s);
    }
}

// ---------------------------------------------------------------------------
extern "C" void kernel_launch(void* const* d_in, const int* in_sizes, int n_in,
                              void* d_out, int out_size, void* d_ws, size_t ws_size,
                              hipStream_t stream) {
    const float* x   = (const float*)d_in[0];
    const int*   ei  = (const int*)d_in[1];
    const float* wm  = (const float*)d_in[2];
    const float* W1  = (const float*)d_in[3];
    const float* b1  = (const float*)d_in[4];
    const float* W2  = (const float*)d_in[5];
    const float* b2  = (const float*)d_in[6];

    const int N = in_sizes[0] / D_IN;   // 50000
    const int E = in_sizes[2];          // 800000
    const int* srcIdx = ei;             // edge_index[0]
    const int* dstIdx = ei + E;         // edge_index[1]

    float* h1   = (float*)d_ws;                    // N*64 floats
    float* agg1 = h1 + (size_t)N * D_HID;          // N*64 floats
    float* h2   = h1;                              // reuse: h1 dead after aggregate1
    float* out  = (float*)d_out;                   // agg2 accumulates here

    hipMemsetAsync(agg1, 0, (size_t)N * D_HID * sizeof(float), stream);
    hipMemsetAsync(out,  0, (size_t)N * D_OUT * sizeof(float), stream);

    gemm1_kernel<<<(N + BM - 1) / BM, 256, 0, stream>>>(x, W1, b1, h1, N);
    aggregate_kernel<D_HID><<<2048, 256, 0, stream>>>(h1, srcIdx, dstIdx, wm, agg1, E);
    gemm2_kernel<<<2048, 256, 0, stream>>>(agg1, W2, b2, h2, N);
    aggregate_kernel<D_OUT><<<2048, 256, 0, stream>>>(h2, srcIdx, dstIdx, wm, out, E);
    logsoftmax_kernel<<<2048, 256, 0, stream>>>(out, N);
}

// Round 3
// 385.450 us; speedup vs baseline: 1.5921x; 1.1511x over previous
//
#include <hip/hip_runtime.h>
#include <math.h>

#define D_IN  512
#define D_HID 64
#define D_OUT 40

// ===========================================================================
// CSR build: counts -> exclusive scan -> scatter (src,w) records by dst.
// Rebuilt every launch (graph-capture determinism; no cross-call state).
// ===========================================================================
__global__ void hist_kernel(const int* __restrict__ dst, int* __restrict__ counts, int E) {
    for (int e = blockIdx.x * blockDim.x + threadIdx.x; e < E;
         e += gridDim.x * blockDim.x)
        atomicAdd(&counts[dst[e]], 1);
}

// inclusive scan within 256-element blocks; row_start[i] = incl, blockSums[b] = total
__global__ __launch_bounds__(256)
void scan1_kernel(const int* __restrict__ counts, int* __restrict__ row_start,
                  int* __restrict__ blockSums, int N) {
    __shared__ int s[256];
    const int t = threadIdx.x;
    const int i = blockIdx.x * 256 + t;
    const int c = (i < N) ? counts[i] : 0;
    s[t] = c;
    __syncthreads();
#pragma unroll
    for (int off = 1; off < 256; off <<= 1) {
        const int v = s[t] + ((t >= off) ? s[t - off] : 0);
        __syncthreads();
        s[t] = v;
        __syncthreads();
    }
    if (i < N) row_start[i] = s[t];
    if (t == 255) blockSums[blockIdx.x] = s[255];
}

// exclusive scan of blockSums (NB <= 256), single block
__global__ __launch_bounds__(256)
void scan2_kernel(int* __restrict__ blockSums, int NB) {
    __shared__ int s[256];
    const int t = threadIdx.x;
    const int c = (t < NB) ? blockSums[t] : 0;
    s[t] = c;
    __syncthreads();
#pragma unroll
    for (int off = 1; off < 256; off <<= 1) {
        const int v = s[t] + ((t >= off) ? s[t - off] : 0);
        __syncthreads();
        s[t] = v;
        __syncthreads();
    }
    if (t < NB) blockSums[t] = s[t] - c;  // exclusive
}

// row_start[i] -> exclusive global offset; cursor copy; row_start[N] = E
__global__ __launch_bounds__(256)
void scan3_kernel(const int* __restrict__ counts, int* __restrict__ row_start,
                  const int* __restrict__ blockSums, int* __restrict__ cursor, int N) {
    const int t = threadIdx.x;
    const int i = blockIdx.x * 256 + t;
    if (i < N) {
        const int c = counts[i];
        const int start = row_start[i] - c + blockSums[blockIdx.x];
        row_start[i] = start;
        cursor[i] = start;
        if (i == N - 1) row_start[N] = start + c;
    }
}

__global__ void scatter_kernel(const int* __restrict__ src, const int* __restrict__ dst,
                               const float* __restrict__ wm, int* __restrict__ cursor,
                               int2* __restrict__ edges, int E) {
    for (int e = blockIdx.x * blockDim.x + threadIdx.x; e < E;
         e += gridDim.x * blockDim.x) {
        const int d = dst[e];
        const int pos = atomicAdd(&cursor[d], 1);
        edges[pos] = make_int2(src[e], __float_as_int(wm[e]));
    }
}

// ===========================================================================
// GEMM1: h1[N,64] = x[N,512] @ W1[512,64] + b1  (register-tiled fp32)
// ===========================================================================
#define BM 256
#define BK 32

__global__ __launch_bounds__(256)
void gemm1_kernel(const float* __restrict__ x, const float* __restrict__ W1,
                  const float* __restrict__ b1, float* __restrict__ h1, int N) {
    __shared__ float xsT[BK][BM + 4];
    __shared__ float ws[BK][D_HID];

    const int t = threadIdx.x;
    const int nodeBase = blockIdx.x * BM;
    const int nb = t >> 3;
    const int cb = t & 7;
    const int kq = t & 7;

    float acc[8][8];
#pragma unroll
    for (int i = 0; i < 8; ++i)
#pragma unroll
        for (int j = 0; j < 8; ++j) acc[i][j] = 0.f;

    for (int k0 = 0; k0 < D_IN; k0 += BK) {
#pragma unroll
        for (int r = 0; r < 8; ++r) {
            const int node = r * 32 + (t >> 3);
            int gn = nodeBase + node;
            if (gn >= N) gn = N - 1;
            const float4 v = *reinterpret_cast<const float4*>(
                x + (size_t)gn * D_IN + k0 + kq * 4);
            xsT[kq * 4 + 0][node] = v.x;
            xsT[kq * 4 + 1][node] = v.y;
            xsT[kq * 4 + 2][node] = v.z;
            xsT[kq * 4 + 3][node] = v.w;
        }
        {
            const float4* wsrc = reinterpret_cast<const float4*>(W1 + (size_t)k0 * D_HID);
            float4* wdst = reinterpret_cast<float4*>(&ws[0][0]);
            wdst[t]       = wsrc[t];
            wdst[t + 256] = wsrc[t + 256];
        }
        __syncthreads();

#pragma unroll 4
        for (int k = 0; k < BK; ++k) {
            const float4 xa = *reinterpret_cast<const float4*>(&xsT[k][nb * 8]);
            const float4 xb = *reinterpret_cast<const float4*>(&xsT[k][nb * 8 + 4]);
            const float4 wa = *reinterpret_cast<const float4*>(&ws[k][cb * 8]);
            const float4 wb = *reinterpret_cast<const float4*>(&ws[k][cb * 8 + 4]);
            const float xv[8] = {xa.x, xa.y, xa.z, xa.w, xb.x, xb.y, xb.z, xb.w};
            const float wv[8] = {wa.x, wa.y, wa.z, wa.w, wb.x, wb.y, wb.z, wb.w};
#pragma unroll
            for (int i = 0; i < 8; ++i)
#pragma unroll
                for (int j = 0; j < 8; ++j)
                    acc[i][j] += xv[i] * wv[j];
        }
        __syncthreads();
    }

    float bb[8];
#pragma unroll
    for (int j = 0; j < 8; ++j) bb[j] = b1[cb * 8 + j];

#pragma unroll
    for (int i = 0; i < 8; ++i) {
        const int gn = nodeBase + nb * 8 + i;
        if (gn < N) {
            float4 o0 = {acc[i][0] + bb[0], acc[i][1] + bb[1],
                         acc[i][2] + bb[2], acc[i][3] + bb[3]};
            float4 o1 = {acc[i][4] + bb[4], acc[i][5] + bb[5],
                         acc[i][6] + bb[6], acc[i][7] + bb[7]};
            float4* dst = reinterpret_cast<float4*>(h1 + (size_t)gn * D_HID + cb * 8);
            dst[0] = o0;
            dst[1] = o1;
        }
    }
}

// ===========================================================================
// CSR aggregation, D_HID channels: wave per node, lane = channel. No atomics.
// ===========================================================================
__global__ __launch_bounds__(256)
void agg_csr_hid(const float* __restrict__ h, const int2* __restrict__ edges,
                 const int* __restrict__ row_start, float* __restrict__ agg, int N) {
    const int lane = threadIdx.x & 63;
    const int n = (blockIdx.x * blockDim.x + threadIdx.x) >> 6;
    if (n >= N) return;
    const int beg = row_start[n];
    const int end = row_start[n + 1];
    float acc = 0.f;
    for (int e = beg; e < end; ++e) {
        const int2 pr = edges[e];
        acc += __int_as_float(pr.y) * h[(size_t)pr.x * D_HID + lane];
    }
    agg[(size_t)n * D_HID + lane] = acc;
}

// ===========================================================================
// GEMM2: h2[N,40] = relu(agg1[N,64]) @ W2[64,40] + b2   (wave per node)
// ===========================================================================
__global__ void gemm2_kernel(const float* __restrict__ agg1,
                             const float* __restrict__ W2,
                             const float* __restrict__ b2,
                             float* __restrict__ h2, int N) {
    __shared__ float w2s[D_HID * D_OUT];
    __shared__ float b2s[D_OUT];
    for (int i = threadIdx.x; i < D_HID * D_OUT; i += blockDim.x) w2s[i] = W2[i];
    if (threadIdx.x < D_OUT) b2s[threadIdx.x] = b2[threadIdx.x];
    __syncthreads();

    const int lane = threadIdx.x & 63;
    const int col  = (lane < D_OUT) ? lane : 0;
    const int gw   = (blockIdx.x * blockDim.x + threadIdx.x) >> 6;
    const int nW   = (gridDim.x * blockDim.x) >> 6;

    for (int n = gw; n < N; n += nW) {
        float acc = b2s[col];
        const float* row = agg1 + (size_t)n * D_HID;
        for (int k = 0; k < D_HID; k += 4) {
            float4 a4 = *reinterpret_cast<const float4*>(row + k);
            acc += fmaxf(a4.x, 0.f) * w2s[(k + 0) * D_OUT + col];
            acc += fmaxf(a4.y, 0.f) * w2s[(k + 1) * D_OUT + col];
            acc += fmaxf(a4.z, 0.f) * w2s[(k + 2) * D_OUT + col];
            acc += fmaxf(a4.w, 0.f) * w2s[(k + 3) * D_OUT + col];
        }
        if (lane < D_OUT) h2[(size_t)n * D_OUT + lane] = acc;
    }
}

// ===========================================================================
// CSR aggregation over D_OUT channels + fused log_softmax. No atomics.
// ===========================================================================
__global__ __launch_bounds__(256)
void agg_csr_out_lsm(const float* __restrict__ h2, const int2* __restrict__ edges,
                     const int* __restrict__ row_start, float* __restrict__ out, int N) {
    const int lane = threadIdx.x & 63;
    const int n = (blockIdx.x * blockDim.x + threadIdx.x) >> 6;
    if (n >= N) return;
    const int beg = row_start[n];
    const int end = row_start[n + 1];
    float acc = 0.f;
    for (int e = beg; e < end; ++e) {
        const int2 pr = edges[e];  // broadcast load, all lanes
        if (lane < D_OUT)
            acc += __int_as_float(pr.y) * h2[(size_t)pr.x * D_OUT + lane];
    }
    const float v = (lane < D_OUT) ? acc : -INFINITY;
    float m = v;
#pragma unroll
    for (int o = 32; o > 0; o >>= 1) m = fmaxf(m, __shfl_xor(m, o, 64));
    float s = (lane < D_OUT) ? __expf(v - m) : 0.f;
#pragma unroll
    for (int o = 32; o > 0; o >>= 1) s += __shfl_xor(s, o, 64);
    if (lane < D_OUT) out[(size_t)n * D_OUT + lane] = v - m - __logf(s);
}

// ===========================================================================
extern "C" void kernel_launch(void* const* d_in, const int* in_sizes, int n_in,
                              void* d_out, int out_size, void* d_ws, size_t ws_size,
                              hipStream_t stream) {
    const float* x   = (const float*)d_in[0];
    const int*   ei  = (const int*)d_in[1];
    const float* wm  = (const float*)d_in[2];
    const float* W1  = (const float*)d_in[3];
    const float* b1  = (const float*)d_in[4];
    const float* W2  = (const float*)d_in[5];
    const float* b2  = (const float*)d_in[6];

    const int N = in_sizes[0] / D_IN;   // 50000
    const int E = in_sizes[2];          // 800000
    const int* srcIdx = ei;
    const int* dstIdx = ei + E;

    // workspace layout
    float* h1        = (float*)d_ws;                    // N*64 f
    float* agg1      = h1 + (size_t)N * D_HID;          // N*64 f
    int2*  edges     = (int2*)(agg1 + (size_t)N * D_HID);  // E int2 (8B aligned)
    int*   row_start = (int*)(edges + E);               // N+1
    int*   cursor    = row_start + (N + 1);             // N
    int*   counts    = cursor + N;                      // N
    int*   blockSums = counts + N;                      // <=256
    float* h2        = h1;                              // reuse: h1 dead after agg1
    float* out       = (float*)d_out;

    const int NB = (N + 255) / 256;  // 196

    // ---- CSR build
    hipMemsetAsync(counts, 0, (size_t)N * sizeof(int), stream);
    hist_kernel<<<1024, 256, 0, stream>>>(dstIdx, counts, E);
    scan1_kernel<<<NB, 256, 0, stream>>>(counts, row_start, blockSums, N);
    scan2_kernel<<<1, 256, 0, stream>>>(blockSums, NB);
    scan3_kernel<<<NB, 256, 0, stream>>>(counts, row_start, blockSums, cursor, N);
    scatter_kernel<<<1024, 256, 0, stream>>>(srcIdx, dstIdx, wm, cursor, edges, E);

    // ---- network
    gemm1_kernel<<<(N + BM - 1) / BM, 256, 0, stream>>>(x, W1, b1, h1, N);
    agg_csr_hid<<<(N * 64 + 255) / 256, 256, 0, stream>>>(h1, edges, row_start, agg1, N);
    gemm2_kernel<<<2048, 256, 0, stream>>>(agg1, W2, b2, h2, N);
    agg_csr_out_lsm<<<(N * 64 + 255) / 256, 256, 0, stream>>>(h2, edges, row_start, out, N);
}

// Round 4
// 321.462 us; speedup vs baseline: 1.9090x; 1.1991x over previous
//
#include <hip/hip_runtime.h>
#include <math.h>

#define D_IN  512
#define D_HID 64
#define D_OUT 40

typedef __attribute__((ext_vector_type(8))) short bf16x8;
typedef __attribute__((ext_vector_type(4))) float f32x4;

static __device__ __forceinline__ unsigned short f2bf(float f) {
    unsigned u = __float_as_uint(f);
    return (unsigned short)((u + 0x7FFF + ((u >> 16) & 1)) >> 16);  // RNE
}
static __device__ __forceinline__ float bf2f(unsigned short h) {
    return __uint_as_float(((unsigned)h) << 16);
}

// ===========================================================================
// CSR build: counts -> exclusive scan -> scatter (src,w) records by dst.
// ===========================================================================
__global__ void hist_kernel(const int* __restrict__ dst, int* __restrict__ counts, int E) {
    for (int e = blockIdx.x * blockDim.x + threadIdx.x; e < E;
         e += gridDim.x * blockDim.x)
        atomicAdd(&counts[dst[e]], 1);
}

__global__ __launch_bounds__(256)
void scan1_kernel(const int* __restrict__ counts, int* __restrict__ row_start,
                  int* __restrict__ blockSums, int N) {
    __shared__ int s[256];
    const int t = threadIdx.x;
    const int i = blockIdx.x * 256 + t;
    const int c = (i < N) ? counts[i] : 0;
    s[t] = c;
    __syncthreads();
#pragma unroll
    for (int off = 1; off < 256; off <<= 1) {
        const int v = s[t] + ((t >= off) ? s[t - off] : 0);
        __syncthreads();
        s[t] = v;
        __syncthreads();
    }
    if (i < N) row_start[i] = s[t];
    if (t == 255) blockSums[blockIdx.x] = s[255];
}

__global__ __launch_bounds__(256)
void scan2_kernel(int* __restrict__ blockSums, int NB) {
    __shared__ int s[256];
    const int t = threadIdx.x;
    const int c = (t < NB) ? blockSums[t] : 0;
    s[t] = c;
    __syncthreads();
#pragma unroll
    for (int off = 1; off < 256; off <<= 1) {
        const int v = s[t] + ((t >= off) ? s[t - off] : 0);
        __syncthreads();
        s[t] = v;
        __syncthreads();
    }
    if (t < NB) blockSums[t] = s[t] - c;
}

__global__ __launch_bounds__(256)
void scan3_kernel(const int* __restrict__ counts, int* __restrict__ row_start,
                  const int* __restrict__ blockSums, int* __restrict__ cursor, int N) {
    const int t = threadIdx.x;
    const int i = blockIdx.x * 256 + t;
    if (i < N) {
        const int c = counts[i];
        const int start = row_start[i] - c + blockSums[blockIdx.x];
        row_start[i] = start;
        cursor[i] = start;
        if (i == N - 1) row_start[N] = start + c;
    }
}

__global__ void scatter_kernel(const int* __restrict__ src, const int* __restrict__ dst,
                               const float* __restrict__ wm, int* __restrict__ cursor,
                               int2* __restrict__ edges, int E) {
    for (int e = blockIdx.x * blockDim.x + threadIdx.x; e < E;
         e += gridDim.x * blockDim.x) {
        const int d = dst[e];
        const int pos = atomicAdd(&cursor[d], 1);
        edges[pos] = make_int2(src[e], __float_as_int(wm[e]));
    }
}

// ===========================================================================
// prep: W1[512][64] fp32 -> w1T[64][512] bf16 (B-operand, contiguous k)
// ===========================================================================
__global__ void prep_w1(const float* __restrict__ W1, unsigned short* __restrict__ w1T) {
    const int i = blockIdx.x * blockDim.x + threadIdx.x;  // i = k*64 + col
    if (i < D_IN * D_HID) {
        const int k = i >> 6, col = i & 63;
        w1T[col * D_IN + k] = f2bf(W1[i]);
    }
}

// ===========================================================================
// GEMM1 (MFMA bf16): h1[N,64](bf16) = x[N,512] @ W1 + b1
// Block = 256 thr (4 waves), BM=64 nodes (16/wave), BK=64.
// LDS 16 KiB: xs[64 rows][64 k] + ws[64 cols][64 k], bf16, row stride 128 B,
// XOR-swizzled 16B granules (byte ^= (row&7)<<4) on BOTH write and read.
// fp32->bf16 conversion fused into x staging.
// ===========================================================================
__global__ __launch_bounds__(256)
void gemm1_mfma(const float* __restrict__ x, const unsigned short* __restrict__ w1T,
                const float* __restrict__ b1, unsigned short* __restrict__ h1, int N) {
    __shared__ unsigned char lds[16384];  // xs @0, ws @8192
    const int t = threadIdx.x;
    const int lane = t & 63;
    const int wv = t >> 6;
    const int nodeBase = blockIdx.x * 64;

    f32x4 acc[4];
#pragma unroll
    for (int cg = 0; cg < 4; ++cg) acc[cg] = (f32x4){0.f, 0.f, 0.f, 0.f};

    for (int k0 = 0; k0 < D_IN; k0 += 64) {
        // ---- stage x tile (fp32 global -> bf16 LDS), 2 granules/thread
#pragma unroll
        for (int hh = 0; hh < 2; ++hh) {
            const int g = t + hh * 256;          // 0..511
            const int row = g >> 3, slot = g & 7;
            int gn = nodeBase + row; if (gn >= N) gn = N - 1;
            const float* sp = x + (size_t)gn * D_IN + k0 + slot * 8;
            const float4 a = *reinterpret_cast<const float4*>(sp);
            const float4 b = *reinterpret_cast<const float4*>(sp + 4);
            uint4 p;
            p.x = (unsigned)f2bf(a.x) | ((unsigned)f2bf(a.y) << 16);
            p.y = (unsigned)f2bf(a.z) | ((unsigned)f2bf(a.w) << 16);
            p.z = (unsigned)f2bf(b.x) | ((unsigned)f2bf(b.y) << 16);
            p.w = (unsigned)f2bf(b.z) | ((unsigned)f2bf(b.w) << 16);
            *reinterpret_cast<uint4*>(lds + row * 128 + ((slot << 4) ^ ((row & 7) << 4))) = p;
        }
        // ---- stage W tile (bf16 global -> bf16 LDS, straight copy)
#pragma unroll
        for (int hh = 0; hh < 2; ++hh) {
            const int g = t + hh * 256;
            const int col = g >> 3, slot = g & 7;
            const uint4 p = *reinterpret_cast<const uint4*>(w1T + (size_t)col * D_IN + k0 + slot * 8);
            *reinterpret_cast<uint4*>(lds + 8192 + col * 128 + ((slot << 4) ^ ((col & 7) << 4))) = p;
        }
        __syncthreads();

        // ---- fragments + MFMA
        const int fr = lane & 15;
        const int fc = lane >> 4;  // k-chunk quarter
#pragma unroll
        for (int s = 0; s < 2; ++s) {
            const int slot = s * 4 + fc;
            const int arow = wv * 16 + fr;
            const bf16x8 afrag = *reinterpret_cast<const bf16x8*>(
                lds + arow * 128 + ((slot << 4) ^ ((arow & 7) << 4)));
#pragma unroll
            for (int cg = 0; cg < 4; ++cg) {
                const int brow = cg * 16 + fr;
                const bf16x8 bfrag = *reinterpret_cast<const bf16x8*>(
                    lds + 8192 + brow * 128 + ((slot << 4) ^ ((brow & 7) << 4)));
                acc[cg] = __builtin_amdgcn_mfma_f32_16x16x32_bf16(afrag, bfrag, acc[cg], 0, 0, 0);
            }
        }
        __syncthreads();
    }

    // ---- epilogue: D[row][col]: col = lane&15 (+16*cg), row = (lane>>4)*4 + reg
    const int fr = lane & 15;
    const int rq = lane >> 4;
#pragma unroll
    for (int cg = 0; cg < 4; ++cg) {
        const int col = cg * 16 + fr;
        const float bb = b1[col];
#pragma unroll
        for (int r = 0; r < 4; ++r) {
            const int node = nodeBase + wv * 16 + rq * 4 + r;
            if (node < N)
                h1[(size_t)node * D_HID + col] = f2bf(acc[cg][r] + bb);
        }
    }
}

// ===========================================================================
// CSR aggregation, 64 ch: wave per node, lane = channel, bf16 gathers.
// ===========================================================================
__global__ __launch_bounds__(256)
void agg_csr_hid(const unsigned short* __restrict__ h, const int2* __restrict__ edges,
                 const int* __restrict__ row_start, float* __restrict__ agg, int N) {
    const int lane = threadIdx.x & 63;
    const int n = (blockIdx.x * blockDim.x + threadIdx.x) >> 6;
    if (n >= N) return;
    const int beg = row_start[n];
    const int end = row_start[n + 1];
    float acc = 0.f;
    for (int e = beg; e < end; ++e) {
        const int2 pr = edges[e];
        acc += __int_as_float(pr.y) * bf2f(h[(size_t)pr.x * D_HID + lane]);
    }
    agg[(size_t)n * D_HID + lane] = acc;
}

// ===========================================================================
// GEMM2: h2[N,40](bf16) = relu(agg1[N,64]) @ W2[64,40] + b2   (wave per node)
// ===========================================================================
__global__ void gemm2_kernel(const float* __restrict__ agg1,
                             const float* __restrict__ W2,
                             const float* __restrict__ b2,
                             unsigned short* __restrict__ h2, int N) {
    __shared__ float w2s[D_HID * D_OUT];
    __shared__ float b2s[D_OUT];
    for (int i = threadIdx.x; i < D_HID * D_OUT; i += blockDim.x) w2s[i] = W2[i];
    if (threadIdx.x < D_OUT) b2s[threadIdx.x] = b2[threadIdx.x];
    __syncthreads();

    const int lane = threadIdx.x & 63;
    const int col  = (lane < D_OUT) ? lane : 0;
    const int gw   = (blockIdx.x * blockDim.x + threadIdx.x) >> 6;
    const int nW   = (gridDim.x * blockDim.x) >> 6;

    for (int n = gw; n < N; n += nW) {
        float acc = b2s[col];
        const float* row = agg1 + (size_t)n * D_HID;
        for (int k = 0; k < D_HID; k += 4) {
            float4 a4 = *reinterpret_cast<const float4*>(row + k);
            acc += fmaxf(a4.x, 0.f) * w2s[(k + 0) * D_OUT + col];
            acc += fmaxf(a4.y, 0.f) * w2s[(k + 1) * D_OUT + col];
            acc += fmaxf(a4.z, 0.f) * w2s[(k + 2) * D_OUT + col];
            acc += fmaxf(a4.w, 0.f) * w2s[(k + 3) * D_OUT + col];
        }
        if (lane < D_OUT) h2[(size_t)n * D_OUT + lane] = f2bf(acc);
    }
}

// ===========================================================================
// CSR aggregation over 40 ch + fused log_softmax, bf16 gathers.
// ===========================================================================
__global__ __launch_bounds__(256)
void agg_csr_out_lsm(const unsigned short* __restrict__ h2, const int2* __restrict__ edges,
                     const int* __restrict__ row_start, float* __restrict__ out, int N) {
    const int lane = threadIdx.x & 63;
    const int n = (blockIdx.x * blockDim.x + threadIdx.x) >> 6;
    if (n >= N) return;
    const int beg = row_start[n];
    const int end = row_start[n + 1];
    float acc = 0.f;
    for (int e = beg; e < end; ++e) {
        const int2 pr = edges[e];
        if (lane < D_OUT)
            acc += __int_as_float(pr.y) * bf2f(h2[(size_t)pr.x * D_OUT + lane]);
    }
    const float v = (lane < D_OUT) ? acc : -INFINITY;
    float m = v;
#pragma unroll
    for (int o = 32; o > 0; o >>= 1) m = fmaxf(m, __shfl_xor(m, o, 64));
    float s = (lane < D_OUT) ? __expf(v - m) : 0.f;
#pragma unroll
    for (int o = 32; o > 0; o >>= 1) s += __shfl_xor(s, o, 64);
    if (lane < D_OUT) out[(size_t)n * D_OUT + lane] = v - m - __logf(s);
}

// ===========================================================================
extern "C" void kernel_launch(void* const* d_in, const int* in_sizes, int n_in,
                              void* d_out, int out_size, void* d_ws, size_t ws_size,
                              hipStream_t stream) {
    const float* x   = (const float*)d_in[0];
    const int*   ei  = (const int*)d_in[1];
    const float* wm  = (const float*)d_in[2];
    const float* W1  = (const float*)d_in[3];
    const float* b1  = (const float*)d_in[4];
    const float* W2  = (const float*)d_in[5];
    const float* b2  = (const float*)d_in[6];

    const int N = in_sizes[0] / D_IN;   // 50000
    const int E = in_sizes[2];          // 800000
    const int* srcIdx = ei;
    const int* dstIdx = ei + E;

    // workspace layout (16B-aligned blocks first)
    unsigned short* w1T  = (unsigned short*)d_ws;                    // 64 KiB
    unsigned short* h1bf = w1T + (size_t)D_HID * D_IN;               // N*64 bf16
    float* agg1          = (float*)(h1bf + (size_t)N * D_HID);       // N*64 f32
    int2*  edges         = (int2*)(agg1 + (size_t)N * D_HID);        // E int2
    int*   row_start     = (int*)(edges + E);                        // N+1
    int*   cursor        = row_start + (N + 1);                      // N
    int*   counts        = cursor + N;                               // N
    int*   blockSums     = counts + N;                               // <=256
    unsigned short* h2bf = h1bf;                                     // reuse
    float* out           = (float*)d_out;

    const int NB = (N + 255) / 256;  // 196

    // ---- CSR build
    hipMemsetAsync(counts, 0, (size_t)N * sizeof(int), stream);
    hist_kernel<<<1024, 256, 0, stream>>>(dstIdx, counts, E);
    scan1_kernel<<<NB, 256, 0, stream>>>(counts, row_start, blockSums, N);
    scan2_kernel<<<1, 256, 0, stream>>>(blockSums, NB);
    scan3_kernel<<<NB, 256, 0, stream>>>(counts, row_start, blockSums, cursor, N);
    scatter_kernel<<<1024, 256, 0, stream>>>(srcIdx, dstIdx, wm, cursor, edges, E);

    // ---- network
    prep_w1<<<(D_IN * D_HID + 255) / 256, 256, 0, stream>>>(W1, w1T);
    gemm1_mfma<<<(N + 63) / 64, 256, 0, stream>>>(x, w1T, b1, h1bf, N);
    agg_csr_hid<<<(N * 64 + 255) / 256, 256, 0, stream>>>(h1bf, edges, row_start, agg1, N);
    gemm2_kernel<<<2048, 256, 0, stream>>>(agg1, W2, b2, h2bf, N);
    agg_csr_out_lsm<<<(N * 64 + 255) / 256, 256, 0, stream>>>(h2bf, edges, row_start, out, N);
}

// Round 5
// 214.292 us; speedup vs baseline: 2.8636x; 1.5001x over previous
//
#include <hip/hip_runtime.h>
#include <math.h>

#define D_IN  512
#define D_HID 64
#define D_OUT 40

typedef __attribute__((ext_vector_type(8))) short bf16x8;
typedef __attribute__((ext_vector_type(4))) float f32x4;

static __device__ __forceinline__ unsigned short f2bf(float f) {
    unsigned u = __float_as_uint(f);
    return (unsigned short)((u + 0x7FFF + ((u >> 16) & 1)) >> 16);  // RNE
}
static __device__ __forceinline__ float bf2f(unsigned short h) {
    return __uint_as_float(((unsigned)h) << 16);
}

// ===========================================================================
// CSR build: counts -> exclusive scan -> scatter (src,w) records by dst.
// ===========================================================================
__global__ void hist_kernel(const int* __restrict__ dst, int* __restrict__ counts, int E) {
    for (int e = blockIdx.x * blockDim.x + threadIdx.x; e < E;
         e += gridDim.x * blockDim.x)
        atomicAdd(&counts[dst[e]], 1);
}

__global__ __launch_bounds__(256)
void scan1_kernel(const int* __restrict__ counts, int* __restrict__ row_start,
                  int* __restrict__ blockSums, int N) {
    __shared__ int s[256];
    const int t = threadIdx.x;
    const int i = blockIdx.x * 256 + t;
    const int c = (i < N) ? counts[i] : 0;
    s[t] = c;
    __syncthreads();
#pragma unroll
    for (int off = 1; off < 256; off <<= 1) {
        const int v = s[t] + ((t >= off) ? s[t - off] : 0);
        __syncthreads();
        s[t] = v;
        __syncthreads();
    }
    if (i < N) row_start[i] = s[t];
    if (t == 255) blockSums[blockIdx.x] = s[255];
}

__global__ __launch_bounds__(256)
void scan2_kernel(int* __restrict__ blockSums, int NB) {
    __shared__ int s[256];
    const int t = threadIdx.x;
    const int c = (t < NB) ? blockSums[t] : 0;
    s[t] = c;
    __syncthreads();
#pragma unroll
    for (int off = 1; off < 256; off <<= 1) {
        const int v = s[t] + ((t >= off) ? s[t - off] : 0);
        __syncthreads();
        s[t] = v;
        __syncthreads();
    }
    if (t < NB) blockSums[t] = s[t] - c;
}

__global__ __launch_bounds__(256)
void scan3_kernel(const int* __restrict__ counts, int* __restrict__ row_start,
                  const int* __restrict__ blockSums, int* __restrict__ cursor, int N) {
    const int t = threadIdx.x;
    const int i = blockIdx.x * 256 + t;
    if (i < N) {
        const int c = counts[i];
        const int start = row_start[i] - c + blockSums[blockIdx.x];
        row_start[i] = start;
        cursor[i] = start;
        if (i == N - 1) row_start[N] = start + c;
    }
}

__global__ void scatter_kernel(const int* __restrict__ src, const int* __restrict__ dst,
                               const float* __restrict__ wm, int* __restrict__ cursor,
                               int2* __restrict__ edges, int E) {
    for (int e = blockIdx.x * blockDim.x + threadIdx.x; e < E;
         e += gridDim.x * blockDim.x) {
        const int d = dst[e];
        const int pos = atomicAdd(&cursor[d], 1);
        edges[pos] = make_int2(src[e], __float_as_int(wm[e]));
    }
}

// ===========================================================================
// prep: W1[512][64] fp32 -> w1T[64][512] bf16 (B-operand, contiguous k)
// ===========================================================================
__global__ void prep_w1(const float* __restrict__ W1, unsigned short* __restrict__ w1T) {
    const int i = blockIdx.x * blockDim.x + threadIdx.x;  // i = k*64 + col
    if (i < D_IN * D_HID) {
        const int k = i >> 6, col = i & 63;
        w1T[col * D_IN + k] = f2bf(W1[i]);
    }
}

// ===========================================================================
// GEMM1 (MFMA bf16): h1[N,64](bf16) = x[N,512] @ W1 + b1
// ===========================================================================
__global__ __launch_bounds__(256)
void gemm1_mfma(const float* __restrict__ x, const unsigned short* __restrict__ w1T,
                const float* __restrict__ b1, unsigned short* __restrict__ h1, int N) {
    __shared__ unsigned char lds[16384];  // xs @0, ws @8192
    const int t = threadIdx.x;
    const int lane = t & 63;
    const int wv = t >> 6;
    const int nodeBase = blockIdx.x * 64;

    f32x4 acc[4];
#pragma unroll
    for (int cg = 0; cg < 4; ++cg) acc[cg] = (f32x4){0.f, 0.f, 0.f, 0.f};

    for (int k0 = 0; k0 < D_IN; k0 += 64) {
#pragma unroll
        for (int hh = 0; hh < 2; ++hh) {
            const int g = t + hh * 256;          // 0..511
            const int row = g >> 3, slot = g & 7;
            int gn = nodeBase + row; if (gn >= N) gn = N - 1;
            const float* sp = x + (size_t)gn * D_IN + k0 + slot * 8;
            const float4 a = *reinterpret_cast<const float4*>(sp);
            const float4 b = *reinterpret_cast<const float4*>(sp + 4);
            uint4 p;
            p.x = (unsigned)f2bf(a.x) | ((unsigned)f2bf(a.y) << 16);
            p.y = (unsigned)f2bf(a.z) | ((unsigned)f2bf(a.w) << 16);
            p.z = (unsigned)f2bf(b.x) | ((unsigned)f2bf(b.y) << 16);
            p.w = (unsigned)f2bf(b.z) | ((unsigned)f2bf(b.w) << 16);
            *reinterpret_cast<uint4*>(lds + row * 128 + ((slot << 4) ^ ((row & 7) << 4))) = p;
        }
#pragma unroll
        for (int hh = 0; hh < 2; ++hh) {
            const int g = t + hh * 256;
            const int col = g >> 3, slot = g & 7;
            const uint4 p = *reinterpret_cast<const uint4*>(w1T + (size_t)col * D_IN + k0 + slot * 8);
            *reinterpret_cast<uint4*>(lds + 8192 + col * 128 + ((slot << 4) ^ ((col & 7) << 4))) = p;
        }
        __syncthreads();

        const int fr = lane & 15;
        const int fc = lane >> 4;
#pragma unroll
        for (int s = 0; s < 2; ++s) {
            const int slot = s * 4 + fc;
            const int arow = wv * 16 + fr;
            const bf16x8 afrag = *reinterpret_cast<const bf16x8*>(
                lds + arow * 128 + ((slot << 4) ^ ((arow & 7) << 4)));
#pragma unroll
            for (int cg = 0; cg < 4; ++cg) {
                const int brow = cg * 16 + fr;
                const bf16x8 bfrag = *reinterpret_cast<const bf16x8*>(
                    lds + 8192 + brow * 128 + ((slot << 4) ^ ((brow & 7) << 4)));
                acc[cg] = __builtin_amdgcn_mfma_f32_16x16x32_bf16(afrag, bfrag, acc[cg], 0, 0, 0);
            }
        }
        __syncthreads();
    }

    const int fr = lane & 15;
    const int rq = lane >> 4;
#pragma unroll
    for (int cg = 0; cg < 4; ++cg) {
        const int col = cg * 16 + fr;
        const float bb = b1[col];
#pragma unroll
        for (int r = 0; r < 4; ++r) {
            const int node = nodeBase + wv * 16 + rq * 4 + r;
            if (node < N)
                h1[(size_t)node * D_HID + col] = f2bf(acc[cg][r] + bb);
        }
    }
}

// ===========================================================================
// CSR aggregation, 64 ch: wave/node, lane=channel. Edge records loaded
// lane-parallel once, broadcast via shfl; 4 independent gathers in flight.
// Fused relu + bf16 store (feeds gemm2).
// ===========================================================================
__global__ __launch_bounds__(256)
void agg_csr_hid(const unsigned short* __restrict__ h, const int2* __restrict__ edges,
                 const int* __restrict__ row_start, unsigned short* __restrict__ agg1, int N) {
    const int lane = threadIdx.x & 63;
    const int n = (blockIdx.x * blockDim.x + threadIdx.x) >> 6;
    if (n >= N) return;
    const int beg = row_start[n];
    const int end = row_start[n + 1];
    float acc = 0.f;
    for (int base = beg; base < end; base += 64) {
        const int cnt = min(64, end - base);
        int2 er = make_int2(0, 0);
        if (base + lane < end) er = edges[base + lane];
        int j = 0;
        for (; j + 4 <= cnt; j += 4) {
            const int   s0 = __shfl(er.x, j + 0), s1 = __shfl(er.x, j + 1);
            const int   s2 = __shfl(er.x, j + 2), s3 = __shfl(er.x, j + 3);
            const float w0 = __int_as_float(__shfl(er.y, j + 0));
            const float w1 = __int_as_float(__shfl(er.y, j + 1));
            const float w2 = __int_as_float(__shfl(er.y, j + 2));
            const float w3 = __int_as_float(__shfl(er.y, j + 3));
            const float v0 = bf2f(h[(size_t)s0 * D_HID + lane]);
            const float v1 = bf2f(h[(size_t)s1 * D_HID + lane]);
            const float v2 = bf2f(h[(size_t)s2 * D_HID + lane]);
            const float v3 = bf2f(h[(size_t)s3 * D_HID + lane]);
            acc += w0 * v0; acc += w1 * v1; acc += w2 * v2; acc += w3 * v3;
        }
        for (; j < cnt; ++j) {
            const int   s0 = __shfl(er.x, j);
            const float w0 = __int_as_float(__shfl(er.y, j));
            acc += w0 * bf2f(h[(size_t)s0 * D_HID + lane]);
        }
    }
    agg1[(size_t)n * D_HID + lane] = f2bf(fmaxf(acc, 0.f));  // fused relu
}

// ===========================================================================
// GEMM2: h2[N,40](bf16) = agg1relu[N,64](bf16) @ W2[64,40] + b2  (wave/node)
// ===========================================================================
__global__ void gemm2_kernel(const unsigned short* __restrict__ agg1,
                             const float* __restrict__ W2,
                             const float* __restrict__ b2,
                             unsigned short* __restrict__ h2, int N) {
    __shared__ float w2s[D_HID * D_OUT];
    __shared__ float b2s[D_OUT];
    for (int i = threadIdx.x; i < D_HID * D_OUT; i += blockDim.x) w2s[i] = W2[i];
    if (threadIdx.x < D_OUT) b2s[threadIdx.x] = b2[threadIdx.x];
    __syncthreads();

    const int lane = threadIdx.x & 63;
    const int col  = (lane < D_OUT) ? lane : 0;
    const int gw   = (blockIdx.x * blockDim.x + threadIdx.x) >> 6;
    const int nW   = (gridDim.x * blockDim.x) >> 6;

    for (int n = gw; n < N; n += nW) {
        float acc = b2s[col];
        const unsigned short* row = agg1 + (size_t)n * D_HID;
#pragma unroll
        for (int k = 0; k < D_HID; k += 8) {
            const uint4 p = *reinterpret_cast<const uint4*>(row + k);  // broadcast 8 bf16
            acc += bf2f((unsigned short)(p.x & 0xffff)) * w2s[(k + 0) * D_OUT + col];
            acc += bf2f((unsigned short)(p.x >> 16))    * w2s[(k + 1) * D_OUT + col];
            acc += bf2f((unsigned short)(p.y & 0xffff)) * w2s[(k + 2) * D_OUT + col];
            acc += bf2f((unsigned short)(p.y >> 16))    * w2s[(k + 3) * D_OUT + col];
            acc += bf2f((unsigned short)(p.z & 0xffff)) * w2s[(k + 4) * D_OUT + col];
            acc += bf2f((unsigned short)(p.z >> 16))    * w2s[(k + 5) * D_OUT + col];
            acc += bf2f((unsigned short)(p.w & 0xffff)) * w2s[(k + 6) * D_OUT + col];
            acc += bf2f((unsigned short)(p.w >> 16))    * w2s[(k + 7) * D_OUT + col];
        }
        if (lane < D_OUT) h2[(size_t)n * D_OUT + lane] = f2bf(acc);
    }
}

// ===========================================================================
// CSR aggregation over 40 ch + fused log_softmax. Shfl-broadcast + unroll 4.
// ===========================================================================
__global__ __launch_bounds__(256)
void agg_csr_out_lsm(const unsigned short* __restrict__ h2, const int2* __restrict__ edges,
                     const int* __restrict__ row_start, float* __restrict__ out, int N) {
    const int lane = threadIdx.x & 63;
    const int col  = (lane < D_OUT) ? lane : 0;  // clamped gather, no branch
    const int n = (blockIdx.x * blockDim.x + threadIdx.x) >> 6;
    if (n >= N) return;
    const int beg = row_start[n];
    const int end = row_start[n + 1];
    float acc = 0.f;
    for (int base = beg; base < end; base += 64) {
        const int cnt = min(64, end - base);
        int2 er = make_int2(0, 0);
        if (base + lane < end) er = edges[base + lane];
        int j = 0;
        for (; j + 4 <= cnt; j += 4) {
            const int   s0 = __shfl(er.x, j + 0), s1 = __shfl(er.x, j + 1);
            const int   s2 = __shfl(er.x, j + 2), s3 = __shfl(er.x, j + 3);
            const float w0 = __int_as_float(__shfl(er.y, j + 0));
            const float w1 = __int_as_float(__shfl(er.y, j + 1));
            const float w2 = __int_as_float(__shfl(er.y, j + 2));
            const float w3 = __int_as_float(__shfl(er.y, j + 3));
            const float v0 = bf2f(h2[(size_t)s0 * D_OUT + col]);
            const float v1 = bf2f(h2[(size_t)s1 * D_OUT + col]);
            const float v2 = bf2f(h2[(size_t)s2 * D_OUT + col]);
            const float v3 = bf2f(h2[(size_t)s3 * D_OUT + col]);
            acc += w0 * v0; acc += w1 * v1; acc += w2 * v2; acc += w3 * v3;
        }
        for (; j < cnt; ++j) {
            const int   s0 = __shfl(er.x, j);
            const float w0 = __int_as_float(__shfl(er.y, j));
            acc += w0 * bf2f(h2[(size_t)s0 * D_OUT + col]);
        }
    }
    const float v = (lane < D_OUT) ? acc : -INFINITY;
    float m = v;
#pragma unroll
    for (int o = 32; o > 0; o >>= 1) m = fmaxf(m, __shfl_xor(m, o, 64));
    float s = (lane < D_OUT) ? __expf(v - m) : 0.f;
#pragma unroll
    for (int o = 32; o > 0; o >>= 1) s += __shfl_xor(s, o, 64);
    if (lane < D_OUT) out[(size_t)n * D_OUT + lane] = v - m - __logf(s);
}

// ===========================================================================
extern "C" void kernel_launch(void* const* d_in, const int* in_sizes, int n_in,
                              void* d_out, int out_size, void* d_ws, size_t ws_size,
                              hipStream_t stream) {
    const float* x   = (const float*)d_in[0];
    const int*   ei  = (const int*)d_in[1];
    const float* wm  = (const float*)d_in[2];
    const float* W1  = (const float*)d_in[3];
    const float* b1  = (const float*)d_in[4];
    const float* W2  = (const float*)d_in[5];
    const float* b2  = (const float*)d_in[6];

    const int N = in_sizes[0] / D_IN;   // 50000
    const int E = in_sizes[2];          // 800000
    const int* srcIdx = ei;
    const int* dstIdx = ei + E;

    // workspace layout (16B-aligned blocks first)
    unsigned short* w1T    = (unsigned short*)d_ws;                  // 64 KiB
    unsigned short* h1bf   = w1T + (size_t)D_HID * D_IN;             // N*64 bf16
    unsigned short* agg1bf = h1bf + (size_t)N * D_HID;               // N*64 bf16
    int2*  edges           = (int2*)(agg1bf + (size_t)N * D_HID);    // E int2
    int*   row_start       = (int*)(edges + E);                      // N+1
    int*   cursor          = row_start + (N + 1);                    // N
    int*   counts          = cursor + N;                             // N
    int*   blockSums       = counts + N;                             // <=256
    unsigned short* h2bf   = h1bf;                                   // reuse
    float* out             = (float*)d_out;

    const int NB = (N + 255) / 256;  // 196

    // ---- CSR build
    hipMemsetAsync(counts, 0, (size_t)N * sizeof(int), stream);
    hist_kernel<<<1024, 256, 0, stream>>>(dstIdx, counts, E);
    scan1_kernel<<<NB, 256, 0, stream>>>(counts, row_start, blockSums, N);
    scan2_kernel<<<1, 256, 0, stream>>>(blockSums, NB);
    scan3_kernel<<<NB, 256, 0, stream>>>(counts, row_start, blockSums, cursor, N);
    scatter_kernel<<<1024, 256, 0, stream>>>(srcIdx, dstIdx, wm, cursor, edges, E);

    // ---- network
    prep_w1<<<(D_IN * D_HID + 255) / 256, 256, 0, stream>>>(W1, w1T);
    gemm1_mfma<<<(N + 63) / 64, 256, 0, stream>>>(x, w1T, b1, h1bf, N);
    agg_csr_hid<<<(N * 64 + 255) / 256, 256, 0, stream>>>(h1bf, edges, row_start, agg1bf, N);
    gemm2_kernel<<<2048, 256, 0, stream>>>(agg1bf, W2, b2, h2bf, N);
    agg_csr_out_lsm<<<(N * 64 + 255) / 256, 256, 0, stream>>>(h2bf, edges, row_start, out, N);
}

// Round 6
// 199.725 us; speedup vs baseline: 3.0725x; 1.0729x over previous
//
#include <hip/hip_runtime.h>
#include <math.h>

#define D_IN  512
#define D_HID 64
#define D_OUT 40

typedef __attribute__((ext_vector_type(8))) short bf16x8;
typedef __attribute__((ext_vector_type(4))) float f32x4;

static __device__ __forceinline__ unsigned short f2bf(float f) {
    unsigned u = __float_as_uint(f);
    return (unsigned short)((u + 0x7FFF + ((u >> 16) & 1)) >> 16);  // RNE
}
static __device__ __forceinline__ float bf2f(unsigned short h) {
    return __uint_as_float(((unsigned)h) << 16);
}

// ===========================================================================
// CSR build, XCD-local: blocks with blockIdx%8==s own dst-slice s, so count
// and CSR-record cache lines are only ever dirtied by ONE XCD's L2
// (round-robin block->XCD heuristic; wrong mapping costs speed, not
// correctness). Each of the 256 edge-chunks is scanned by 8 blocks.
// ===========================================================================
__global__ __launch_bounds__(256)
void hist_xcd(const int* __restrict__ dst, int* __restrict__ counts, int E, int N) {
    const int slice = (N + 7) >> 3;
    const int lo = (blockIdx.x & 7) * slice;
    const int hi = min(N, lo + slice);
    const int nChunk = gridDim.x >> 3;
    const int per = (E + nChunk - 1) / nChunk;
    const int beg = (blockIdx.x >> 3) * per;
    const int end = min(E, beg + per);
    for (int e = beg + threadIdx.x; e < end; e += blockDim.x) {
        const int d = dst[e];
        if (d >= lo && d < hi) atomicAdd(&counts[d], 1);
    }
}

__global__ __launch_bounds__(256)
void scatter_xcd(const int* __restrict__ src, const int* __restrict__ dstA,
                 const float* __restrict__ wm, int* __restrict__ cursor,
                 int2* __restrict__ edges, int E, int N) {
    const int slice = (N + 7) >> 3;
    const int lo = (blockIdx.x & 7) * slice;
    const int hi = min(N, lo + slice);
    const int nChunk = gridDim.x >> 3;
    const int per = (E + nChunk - 1) / nChunk;
    const int beg = (blockIdx.x >> 3) * per;
    const int end = min(E, beg + per);
    for (int e = beg + threadIdx.x; e < end; e += blockDim.x) {
        const int d = dstA[e];
        if (d >= lo && d < hi) {
            const int pos = atomicAdd(&cursor[d], 1);
            edges[pos] = make_int2(src[e], __float_as_int(wm[e]));
        }
    }
}

__global__ __launch_bounds__(256)
void scan1_kernel(const int* __restrict__ counts, int* __restrict__ row_start,
                  int* __restrict__ blockSums, int N) {
    __shared__ int s[256];
    const int t = threadIdx.x;
    const int i = blockIdx.x * 256 + t;
    const int c = (i < N) ? counts[i] : 0;
    s[t] = c;
    __syncthreads();
#pragma unroll
    for (int off = 1; off < 256; off <<= 1) {
        const int v = s[t] + ((t >= off) ? s[t - off] : 0);
        __syncthreads();
        s[t] = v;
        __syncthreads();
    }
    if (i < N) row_start[i] = s[t];
    if (t == 255) blockSums[blockIdx.x] = s[255];
}

__global__ __launch_bounds__(256)
void scan2_kernel(int* __restrict__ blockSums, int NB) {
    __shared__ int s[256];
    const int t = threadIdx.x;
    const int c = (t < NB) ? blockSums[t] : 0;
    s[t] = c;
    __syncthreads();
#pragma unroll
    for (int off = 1; off < 256; off <<= 1) {
        const int v = s[t] + ((t >= off) ? s[t - off] : 0);
        __syncthreads();
        s[t] = v;
        __syncthreads();
    }
    if (t < NB) blockSums[t] = s[t] - c;
}

__global__ __launch_bounds__(256)
void scan3_kernel(const int* __restrict__ counts, int* __restrict__ row_start,
                  const int* __restrict__ blockSums, int* __restrict__ cursor, int N) {
    const int t = threadIdx.x;
    const int i = blockIdx.x * 256 + t;
    if (i < N) {
        const int c = counts[i];
        const int start = row_start[i] - c + blockSums[blockIdx.x];
        row_start[i] = start;
        cursor[i] = start;
        if (i == N - 1) row_start[N] = start + c;
    }
}

// ===========================================================================
// prep: W1[512][64] fp32 -> w1T[64][512] bf16 (B-operand, contiguous k)
// ===========================================================================
__global__ void prep_w1(const float* __restrict__ W1, unsigned short* __restrict__ w1T) {
    const int i = blockIdx.x * blockDim.x + threadIdx.x;  // i = k*64 + col
    if (i < D_IN * D_HID) {
        const int k = i >> 6, col = i & 63;
        w1T[col * D_IN + k] = f2bf(W1[i]);
    }
}

// ===========================================================================
// GEMM1 (MFMA bf16): h1[N,64](bf16) = x[N,512] @ W1 + b1
// ===========================================================================
__global__ __launch_bounds__(256)
void gemm1_mfma(const float* __restrict__ x, const unsigned short* __restrict__ w1T,
                const float* __restrict__ b1, unsigned short* __restrict__ h1, int N) {
    __shared__ unsigned char lds[16384];  // xs @0, ws @8192
    const int t = threadIdx.x;
    const int lane = t & 63;
    const int wv = t >> 6;
    const int nodeBase = blockIdx.x * 64;

    f32x4 acc[4];
#pragma unroll
    for (int cg = 0; cg < 4; ++cg) acc[cg] = (f32x4){0.f, 0.f, 0.f, 0.f};

    for (int k0 = 0; k0 < D_IN; k0 += 64) {
#pragma unroll
        for (int hh = 0; hh < 2; ++hh) {
            const int g = t + hh * 256;          // 0..511
            const int row = g >> 3, slot = g & 7;
            int gn = nodeBase + row; if (gn >= N) gn = N - 1;
            const float* sp = x + (size_t)gn * D_IN + k0 + slot * 8;
            const float4 a = *reinterpret_cast<const float4*>(sp);
            const float4 b = *reinterpret_cast<const float4*>(sp + 4);
            uint4 p;
            p.x = (unsigned)f2bf(a.x) | ((unsigned)f2bf(a.y) << 16);
            p.y = (unsigned)f2bf(a.z) | ((unsigned)f2bf(a.w) << 16);
            p.z = (unsigned)f2bf(b.x) | ((unsigned)f2bf(b.y) << 16);
            p.w = (unsigned)f2bf(b.z) | ((unsigned)f2bf(b.w) << 16);
            *reinterpret_cast<uint4*>(lds + row * 128 + ((slot << 4) ^ ((row & 7) << 4))) = p;
        }
#pragma unroll
        for (int hh = 0; hh < 2; ++hh) {
            const int g = t + hh * 256;
            const int col = g >> 3, slot = g & 7;
            const uint4 p = *reinterpret_cast<const uint4*>(w1T + (size_t)col * D_IN + k0 + slot * 8);
            *reinterpret_cast<uint4*>(lds + 8192 + col * 128 + ((slot << 4) ^ ((col & 7) << 4))) = p;
        }
        __syncthreads();

        const int fr = lane & 15;
        const int fc = lane >> 4;
#pragma unroll
        for (int s = 0; s < 2; ++s) {
            const int slot = s * 4 + fc;
            const int arow = wv * 16 + fr;
            const bf16x8 afrag = *reinterpret_cast<const bf16x8*>(
                lds + arow * 128 + ((slot << 4) ^ ((arow & 7) << 4)));
#pragma unroll
            for (int cg = 0; cg < 4; ++cg) {
                const int brow = cg * 16 + fr;
                const bf16x8 bfrag = *reinterpret_cast<const bf16x8*>(
                    lds + 8192 + brow * 128 + ((slot << 4) ^ ((brow & 7) << 4)));
                acc[cg] = __builtin_amdgcn_mfma_f32_16x16x32_bf16(afrag, bfrag, acc[cg], 0, 0, 0);
            }
        }
        __syncthreads();
    }

    const int fr = lane & 15;
    const int rq = lane >> 4;
#pragma unroll
    for (int cg = 0; cg < 4; ++cg) {
        const int col = cg * 16 + fr;
        const float bb = b1[col];
#pragma unroll
        for (int r = 0; r < 4; ++r) {
            const int node = nodeBase + wv * 16 + rq * 4 + r;
            if (node < N)
                h1[(size_t)node * D_HID + col] = f2bf(acc[cg][r] + bb);
        }
    }
}

// ===========================================================================
// CSR aggregation, 64 ch: wave/node, lane=channel. Edge records loaded
// lane-parallel once, broadcast via shfl; 4 independent gathers in flight.
// Fused relu + bf16 store (feeds gemm2).
// ===========================================================================
__global__ __launch_bounds__(256)
void agg_csr_hid(const unsigned short* __restrict__ h, const int2* __restrict__ edges,
                 const int* __restrict__ row_start, unsigned short* __restrict__ agg1, int N) {
    const int lane = threadIdx.x & 63;
    const int n = (blockIdx.x * blockDim.x + threadIdx.x) >> 6;
    if (n >= N) return;
    const int beg = row_start[n];
    const int end = row_start[n + 1];
    float acc = 0.f;
    for (int base = beg; base < end; base += 64) {
        const int cnt = min(64, end - base);
        int2 er = make_int2(0, 0);
        if (base + lane < end) er = edges[base + lane];
        int j = 0;
        for (; j + 4 <= cnt; j += 4) {
            const int   s0 = __shfl(er.x, j + 0), s1 = __shfl(er.x, j + 1);
            const int   s2 = __shfl(er.x, j + 2), s3 = __shfl(er.x, j + 3);
            const float w0 = __int_as_float(__shfl(er.y, j + 0));
            const float w1 = __int_as_float(__shfl(er.y, j + 1));
            const float w2 = __int_as_float(__shfl(er.y, j + 2));
            const float w3 = __int_as_float(__shfl(er.y, j + 3));
            const float v0 = bf2f(h[(size_t)s0 * D_HID + lane]);
            const float v1 = bf2f(h[(size_t)s1 * D_HID + lane]);
            const float v2 = bf2f(h[(size_t)s2 * D_HID + lane]);
            const float v3 = bf2f(h[(size_t)s3 * D_HID + lane]);
            acc += w0 * v0; acc += w1 * v1; acc += w2 * v2; acc += w3 * v3;
        }
        for (; j < cnt; ++j) {
            const int   s0 = __shfl(er.x, j);
            const float w0 = __int_as_float(__shfl(er.y, j));
            acc += w0 * bf2f(h[(size_t)s0 * D_HID + lane]);
        }
    }
    agg1[(size_t)n * D_HID + lane] = f2bf(fmaxf(acc, 0.f));  // fused relu
}

// ===========================================================================
// GEMM2: h2[N,40](bf16) = agg1relu[N,64](bf16) @ W2[64,40] + b2  (wave/node)
// ===========================================================================
__global__ void gemm2_kernel(const unsigned short* __restrict__ agg1,
                             const float* __restrict__ W2,
                             const float* __restrict__ b2,
                             unsigned short* __restrict__ h2, int N) {
    __shared__ float w2s[D_HID * D_OUT];
    __shared__ float b2s[D_OUT];
    for (int i = threadIdx.x; i < D_HID * D_OUT; i += blockDim.x) w2s[i] = W2[i];
    if (threadIdx.x < D_OUT) b2s[threadIdx.x] = b2[threadIdx.x];
    __syncthreads();

    const int lane = threadIdx.x & 63;
    const int col  = (lane < D_OUT) ? lane : 0;
    const int gw   = (blockIdx.x * blockDim.x + threadIdx.x) >> 6;
    const int nW   = (gridDim.x * blockDim.x) >> 6;

    for (int n = gw; n < N; n += nW) {
        float acc = b2s[col];
        const unsigned short* row = agg1 + (size_t)n * D_HID;
#pragma unroll
        for (int k = 0; k < D_HID; k += 8) {
            const uint4 p = *reinterpret_cast<const uint4*>(row + k);  // broadcast 8 bf16
            acc += bf2f((unsigned short)(p.x & 0xffff)) * w2s[(k + 0) * D_OUT + col];
            acc += bf2f((unsigned short)(p.x >> 16))    * w2s[(k + 1) * D_OUT + col];
            acc += bf2f((unsigned short)(p.y & 0xffff)) * w2s[(k + 2) * D_OUT + col];
            acc += bf2f((unsigned short)(p.y >> 16))    * w2s[(k + 3) * D_OUT + col];
            acc += bf2f((unsigned short)(p.z & 0xffff)) * w2s[(k + 4) * D_OUT + col];
            acc += bf2f((unsigned short)(p.z >> 16))    * w2s[(k + 5) * D_OUT + col];
            acc += bf2f((unsigned short)(p.w & 0xffff)) * w2s[(k + 6) * D_OUT + col];
            acc += bf2f((unsigned short)(p.w >> 16))    * w2s[(k + 7) * D_OUT + col];
        }
        if (lane < D_OUT) h2[(size_t)n * D_OUT + lane] = f2bf(acc);
    }
}

// ===========================================================================
// CSR aggregation over 40 ch + fused log_softmax. Shfl-broadcast + unroll 4.
// ===========================================================================
__global__ __launch_bounds__(256)
void agg_csr_out_lsm(const unsigned short* __restrict__ h2, const int2* __restrict__ edges,
                     const int* __restrict__ row_start, float* __restrict__ out, int N) {
    const int lane = threadIdx.x & 63;
    const int col  = (lane < D_OUT) ? lane : 0;  // clamped gather, no branch
    const int n = (blockIdx.x * blockDim.x + threadIdx.x) >> 6;
    if (n >= N) return;
    const int beg = row_start[n];
    const int end = row_start[n + 1];
    float acc = 0.f;
    for (int base = beg; base < end; base += 64) {
        const int cnt = min(64, end - base);
        int2 er = make_int2(0, 0);
        if (base + lane < end) er = edges[base + lane];
        int j = 0;
        for (; j + 4 <= cnt; j += 4) {
            const int   s0 = __shfl(er.x, j + 0), s1 = __shfl(er.x, j + 1);
            const int   s2 = __shfl(er.x, j + 2), s3 = __shfl(er.x, j + 3);
            const float w0 = __int_as_float(__shfl(er.y, j + 0));
            const float w1 = __int_as_float(__shfl(er.y, j + 1));
            const float w2 = __int_as_float(__shfl(er.y, j + 2));
            const float w3 = __int_as_float(__shfl(er.y, j + 3));
            const float v0 = bf2f(h2[(size_t)s0 * D_OUT + col]);
            const float v1 = bf2f(h2[(size_t)s1 * D_OUT + col]);
            const float v2 = bf2f(h2[(size_t)s2 * D_OUT + col]);
            const float v3 = bf2f(h2[(size_t)s3 * D_OUT + col]);
            acc += w0 * v0; acc += w1 * v1; acc += w2 * v2; acc += w3 * v3;
        }
        for (; j < cnt; ++j) {
            const int   s0 = __shfl(er.x, j);
            const float w0 = __int_as_float(__shfl(er.y, j));
            acc += w0 * bf2f(h2[(size_t)s0 * D_OUT + col]);
        }
    }
    const float v = (lane < D_OUT) ? acc : -INFINITY;
    float m = v;
#pragma unroll
    for (int o = 32; o > 0; o >>= 1) m = fmaxf(m, __shfl_xor(m, o, 64));
    float s = (lane < D_OUT) ? __expf(v - m) : 0.f;
#pragma unroll
    for (int o = 32; o > 0; o >>= 1) s += __shfl_xor(s, o, 64);
    if (lane < D_OUT) out[(size_t)n * D_OUT + lane] = v - m - __logf(s);
}

// ===========================================================================
extern "C" void kernel_launch(void* const* d_in, const int* in_sizes, int n_in,
                              void* d_out, int out_size, void* d_ws, size_t ws_size,
                              hipStream_t stream) {
    const float* x   = (const float*)d_in[0];
    const int*   ei  = (const int*)d_in[1];
    const float* wm  = (const float*)d_in[2];
    const float* W1  = (const float*)d_in[3];
    const float* b1  = (const float*)d_in[4];
    const float* W2  = (const float*)d_in[5];
    const float* b2  = (const float*)d_in[6];

    const int N = in_sizes[0] / D_IN;   // 50000
    const int E = in_sizes[2];          // 800000
    const int* srcIdx = ei;
    const int* dstIdx = ei + E;

    // workspace layout (16B-aligned blocks first)
    unsigned short* w1T    = (unsigned short*)d_ws;                  // 64 KiB
    unsigned short* h1bf   = w1T + (size_t)D_HID * D_IN;             // N*64 bf16
    unsigned short* agg1bf = h1bf + (size_t)N * D_HID;               // N*64 bf16
    int2*  edges           = (int2*)(agg1bf + (size_t)N * D_HID);    // E int2
    int*   row_start       = (int*)(edges + E);                      // N+1
    int*   cursor          = row_start + (N + 1);                    // N
    int*   counts          = cursor + N;                             // N
    int*   blockSums       = counts + N;                             // <=256
    unsigned short* h2bf   = h1bf;                                   // reuse
    float* out             = (float*)d_out;

    const int NB = (N + 255) / 256;  // 196

    // ---- CSR build (XCD-local hist + scatter)
    hipMemsetAsync(counts, 0, (size_t)N * sizeof(int), stream);
    hist_xcd<<<2048, 256, 0, stream>>>(dstIdx, counts, E, N);
    scan1_kernel<<<NB, 256, 0, stream>>>(counts, row_start, blockSums, N);
    scan2_kernel<<<1, 256, 0, stream>>>(blockSums, NB);
    scan3_kernel<<<NB, 256, 0, stream>>>(counts, row_start, blockSums, cursor, N);
    scatter_xcd<<<2048, 256, 0, stream>>>(srcIdx, dstIdx, wm, cursor, edges, E, N);

    // ---- network
    prep_w1<<<(D_IN * D_HID + 255) / 256, 256, 0, stream>>>(W1, w1T);
    gemm1_mfma<<<(N + 63) / 64, 256, 0, stream>>>(x, w1T, b1, h1bf, N);
    agg_csr_hid<<<(N * 64 + 255) / 256, 256, 0, stream>>>(h1bf, edges, row_start, agg1bf, N);
    gemm2_kernel<<<2048, 256, 0, stream>>>(agg1bf, W2, b2, h2bf, N);
    agg_csr_out_lsm<<<(N * 64 + 255) / 256, 256, 0, stream>>>(h2bf, edges, row_start, out, N);
}

// Round 7
// 193.316 us; speedup vs baseline: 3.1744x; 1.0332x over previous
//
#include <hip/hip_runtime.h>
#include <math.h>

#define D_IN  512
#define D_HID 64
#define D_OUT 40

typedef __attribute__((ext_vector_type(8))) short bf16x8;
typedef __attribute__((ext_vector_type(4))) float f32x4;

static __device__ __forceinline__ unsigned short f2bf(float f) {
    unsigned u = __float_as_uint(f);
    return (unsigned short)((u + 0x7FFF + ((u >> 16) & 1)) >> 16);  // RNE
}
static __device__ __forceinline__ float bf2f(unsigned short h) {
    return __uint_as_float(((unsigned)h) << 16);
}

// ===========================================================================
// zero counts ourselves: runtime's fillBufferAligned ran this 200 KB fill at
// 3.5 GB/s (57 us/launch, rocprof r6). Grid-stride int fill ~1-2 us.
// ===========================================================================
__global__ __launch_bounds__(256)
void zero_counts(int* __restrict__ counts, int N) {
    const int i = blockIdx.x * blockDim.x + threadIdx.x;
    if (i < N) counts[i] = 0;
}

// ===========================================================================
// CSR build, XCD-local: blocks with blockIdx%8==s own dst-slice s, so count
// and CSR-record cache lines are only ever dirtied by ONE XCD's L2.
// ===========================================================================
__global__ __launch_bounds__(256)
void hist_xcd(const int* __restrict__ dst, int* __restrict__ counts, int E, int N) {
    const int slice = (N + 7) >> 3;
    const int lo = (blockIdx.x & 7) * slice;
    const int hi = min(N, lo + slice);
    const int nChunk = gridDim.x >> 3;
    const int per = (E + nChunk - 1) / nChunk;
    const int beg = (blockIdx.x >> 3) * per;
    const int end = min(E, beg + per);
    for (int e = beg + threadIdx.x; e < end; e += blockDim.x) {
        const int d = dst[e];
        if (d >= lo && d < hi) atomicAdd(&counts[d], 1);
    }
}

__global__ __launch_bounds__(256)
void scatter_xcd(const int* __restrict__ src, const int* __restrict__ dstA,
                 const float* __restrict__ wm, int* __restrict__ cursor,
                 int2* __restrict__ edges, int E, int N) {
    const int slice = (N + 7) >> 3;
    const int lo = (blockIdx.x & 7) * slice;
    const int hi = min(N, lo + slice);
    const int nChunk = gridDim.x >> 3;
    const int per = (E + nChunk - 1) / nChunk;
    const int beg = (blockIdx.x >> 3) * per;
    const int end = min(E, beg + per);
    for (int e = beg + threadIdx.x; e < end; e += blockDim.x) {
        const int d = dstA[e];
        if (d >= lo && d < hi) {
            const int pos = atomicAdd(&cursor[d], 1);
            edges[pos] = make_int2(src[e], __float_as_int(wm[e]));
        }
    }
}

__global__ __launch_bounds__(256)
void scan1_kernel(const int* __restrict__ counts, int* __restrict__ row_start,
                  int* __restrict__ blockSums, int N) {
    __shared__ int s[256];
    const int t = threadIdx.x;
    const int i = blockIdx.x * 256 + t;
    const int c = (i < N) ? counts[i] : 0;
    s[t] = c;
    __syncthreads();
#pragma unroll
    for (int off = 1; off < 256; off <<= 1) {
        const int v = s[t] + ((t >= off) ? s[t - off] : 0);
        __syncthreads();
        s[t] = v;
        __syncthreads();
    }
    if (i < N) row_start[i] = s[t];
    if (t == 255) blockSums[blockIdx.x] = s[255];
}

__global__ __launch_bounds__(256)
void scan2_kernel(int* __restrict__ blockSums, int NB) {
    __shared__ int s[256];
    const int t = threadIdx.x;
    const int c = (t < NB) ? blockSums[t] : 0;
    s[t] = c;
    __syncthreads();
#pragma unroll
    for (int off = 1; off < 256; off <<= 1) {
        const int v = s[t] + ((t >= off) ? s[t - off] : 0);
        __syncthreads();
        s[t] = v;
        __syncthreads();
    }
    if (t < NB) blockSums[t] = s[t] - c;
}

__global__ __launch_bounds__(256)
void scan3_kernel(const int* __restrict__ counts, int* __restrict__ row_start,
                  const int* __restrict__ blockSums, int* __restrict__ cursor, int N) {
    const int t = threadIdx.x;
    const int i = blockIdx.x * 256 + t;
    if (i < N) {
        const int c = counts[i];
        const int start = row_start[i] - c + blockSums[blockIdx.x];
        row_start[i] = start;
        cursor[i] = start;
        if (i == N - 1) row_start[N] = start + c;
    }
}

// ===========================================================================
// prep: W1[512][64] fp32 -> w1T[64][512] bf16 (B-operand, contiguous k)
// ===========================================================================
__global__ void prep_w1(const float* __restrict__ W1, unsigned short* __restrict__ w1T) {
    const int i = blockIdx.x * blockDim.x + threadIdx.x;  // i = k*64 + col
    if (i < D_IN * D_HID) {
        const int k = i >> 6, col = i & 63;
        w1T[col * D_IN + k] = f2bf(W1[i]);
    }
}

// ===========================================================================
// GEMM1 (MFMA bf16): h1[N,64](bf16) = x[N,512] @ W1 + b1
// ===========================================================================
__global__ __launch_bounds__(256)
void gemm1_mfma(const float* __restrict__ x, const unsigned short* __restrict__ w1T,
                const float* __restrict__ b1, unsigned short* __restrict__ h1, int N) {
    __shared__ unsigned char lds[16384];  // xs @0, ws @8192
    const int t = threadIdx.x;
    const int lane = t & 63;
    const int wv = t >> 6;
    const int nodeBase = blockIdx.x * 64;

    f32x4 acc[4];
#pragma unroll
    for (int cg = 0; cg < 4; ++cg) acc[cg] = (f32x4){0.f, 0.f, 0.f, 0.f};

    for (int k0 = 0; k0 < D_IN; k0 += 64) {
#pragma unroll
        for (int hh = 0; hh < 2; ++hh) {
            const int g = t + hh * 256;          // 0..511
            const int row = g >> 3, slot = g & 7;
            int gn = nodeBase + row; if (gn >= N) gn = N - 1;
            const float* sp = x + (size_t)gn * D_IN + k0 + slot * 8;
            const float4 a = *reinterpret_cast<const float4*>(sp);
            const float4 b = *reinterpret_cast<const float4*>(sp + 4);
            uint4 p;
            p.x = (unsigned)f2bf(a.x) | ((unsigned)f2bf(a.y) << 16);
            p.y = (unsigned)f2bf(a.z) | ((unsigned)f2bf(a.w) << 16);
            p.z = (unsigned)f2bf(b.x) | ((unsigned)f2bf(b.y) << 16);
            p.w = (unsigned)f2bf(b.z) | ((unsigned)f2bf(b.w) << 16);
            *reinterpret_cast<uint4*>(lds + row * 128 + ((slot << 4) ^ ((row & 7) << 4))) = p;
        }
#pragma unroll
        for (int hh = 0; hh < 2; ++hh) {
            const int g = t + hh * 256;
            const int col = g >> 3, slot = g & 7;
            const uint4 p = *reinterpret_cast<const uint4*>(w1T + (size_t)col * D_IN + k0 + slot * 8);
            *reinterpret_cast<uint4*>(lds + 8192 + col * 128 + ((slot << 4) ^ ((col & 7) << 4))) = p;
        }
        __syncthreads();

        const int fr = lane & 15;
        const int fc = lane >> 4;
#pragma unroll
        for (int s = 0; s < 2; ++s) {
            const int slot = s * 4 + fc;
            const int arow = wv * 16 + fr;
            const bf16x8 afrag = *reinterpret_cast<const bf16x8*>(
                lds + arow * 128 + ((slot << 4) ^ ((arow & 7) << 4)));
#pragma unroll
            for (int cg = 0; cg < 4; ++cg) {
                const int brow = cg * 16 + fr;
                const bf16x8 bfrag = *reinterpret_cast<const bf16x8*>(
                    lds + 8192 + brow * 128 + ((slot << 4) ^ ((brow & 7) << 4)));
                acc[cg] = __builtin_amdgcn_mfma_f32_16x16x32_bf16(afrag, bfrag, acc[cg], 0, 0, 0);
            }
        }
        __syncthreads();
    }

    const int fr = lane & 15;
    const int rq = lane >> 4;
#pragma unroll
    for (int cg = 0; cg < 4; ++cg) {
        const int col = cg * 16 + fr;
        const float bb = b1[col];
#pragma unroll
        for (int r = 0; r < 4; ++r) {
            const int node = nodeBase + wv * 16 + rq * 4 + r;
            if (node < N)
                h1[(size_t)node * D_HID + col] = f2bf(acc[cg][r] + bb);
        }
    }
}

// ===========================================================================
// CSR aggregation, 64 ch: wave/node, lane=channel. Shfl-broadcast edge
// records; 4 independent gathers in flight. Fused relu + bf16 store.
// ===========================================================================
__global__ __launch_bounds__(256)
void agg_csr_hid(const unsigned short* __restrict__ h, const int2* __restrict__ edges,
                 const int* __restrict__ row_start, unsigned short* __restrict__ agg1, int N) {
    const int lane = threadIdx.x & 63;
    const int n = (blockIdx.x * blockDim.x + threadIdx.x) >> 6;
    if (n >= N) return;
    const int beg = row_start[n];
    const int end = row_start[n + 1];
    float acc = 0.f;
    for (int base = beg; base < end; base += 64) {
        const int cnt = min(64, end - base);
        int2 er = make_int2(0, 0);
        if (base + lane < end) er = edges[base + lane];
        int j = 0;
        for (; j + 4 <= cnt; j += 4) {
            const int   s0 = __shfl(er.x, j + 0), s1 = __shfl(er.x, j + 1);
            const int   s2 = __shfl(er.x, j + 2), s3 = __shfl(er.x, j + 3);
            const float w0 = __int_as_float(__shfl(er.y, j + 0));
            const float w1 = __int_as_float(__shfl(er.y, j + 1));
            const float w2 = __int_as_float(__shfl(er.y, j + 2));
            const float w3 = __int_as_float(__shfl(er.y, j + 3));
            const float v0 = bf2f(h[(size_t)s0 * D_HID + lane]);
            const float v1 = bf2f(h[(size_t)s1 * D_HID + lane]);
            const float v2 = bf2f(h[(size_t)s2 * D_HID + lane]);
            const float v3 = bf2f(h[(size_t)s3 * D_HID + lane]);
            acc += w0 * v0; acc += w1 * v1; acc += w2 * v2; acc += w3 * v3;
        }
        for (; j < cnt; ++j) {
            const int   s0 = __shfl(er.x, j);
            const float w0 = __int_as_float(__shfl(er.y, j));
            acc += w0 * bf2f(h[(size_t)s0 * D_HID + lane]);
        }
    }
    agg1[(size_t)n * D_HID + lane] = f2bf(fmaxf(acc, 0.f));  // fused relu
}

// ===========================================================================
// GEMM2: h2[N,40](bf16) = agg1relu[N,64](bf16) @ W2[64,40] + b2  (wave/node)
// ===========================================================================
__global__ void gemm2_kernel(const unsigned short* __restrict__ agg1,
                             const float* __restrict__ W2,
                             const float* __restrict__ b2,
                             unsigned short* __restrict__ h2, int N) {
    __shared__ float w2s[D_HID * D_OUT];
    __shared__ float b2s[D_OUT];
    for (int i = threadIdx.x; i < D_HID * D_OUT; i += blockDim.x) w2s[i] = W2[i];
    if (threadIdx.x < D_OUT) b2s[threadIdx.x] = b2[threadIdx.x];
    __syncthreads();

    const int lane = threadIdx.x & 63;
    const int col  = (lane < D_OUT) ? lane : 0;
    const int gw   = (blockIdx.x * blockDim.x + threadIdx.x) >> 6;
    const int nW   = (gridDim.x * blockDim.x) >> 6;

    for (int n = gw; n < N; n += nW) {
        float acc = b2s[col];
        const unsigned short* row = agg1 + (size_t)n * D_HID;
#pragma unroll
        for (int k = 0; k < D_HID; k += 8) {
            const uint4 p = *reinterpret_cast<const uint4*>(row + k);  // broadcast 8 bf16
            acc += bf2f((unsigned short)(p.x & 0xffff)) * w2s[(k + 0) * D_OUT + col];
            acc += bf2f((unsigned short)(p.x >> 16))    * w2s[(k + 1) * D_OUT + col];
            acc += bf2f((unsigned short)(p.y & 0xffff)) * w2s[(k + 2) * D_OUT + col];
            acc += bf2f((unsigned short)(p.y >> 16))    * w2s[(k + 3) * D_OUT + col];
            acc += bf2f((unsigned short)(p.z & 0xffff)) * w2s[(k + 4) * D_OUT + col];
            acc += bf2f((unsigned short)(p.z >> 16))    * w2s[(k + 5) * D_OUT + col];
            acc += bf2f((unsigned short)(p.w & 0xffff)) * w2s[(k + 6) * D_OUT + col];
            acc += bf2f((unsigned short)(p.w >> 16))    * w2s[(k + 7) * D_OUT + col];
        }
        if (lane < D_OUT) h2[(size_t)n * D_OUT + lane] = f2bf(acc);
    }
}

// ===========================================================================
// CSR aggregation over 40 ch + fused log_softmax. Shfl-broadcast + unroll 4.
// ===========================================================================
__global__ __launch_bounds__(256)
void agg_csr_out_lsm(const unsigned short* __restrict__ h2, const int2* __restrict__ edges,
                     const int* __restrict__ row_start, float* __restrict__ out, int N) {
    const int lane = threadIdx.x & 63;
    const int col  = (lane < D_OUT) ? lane : 0;  // clamped gather, no branch
    const int n = (blockIdx.x * blockDim.x + threadIdx.x) >> 6;
    if (n >= N) return;
    const int beg = row_start[n];
    const int end = row_start[n + 1];
    float acc = 0.f;
    for (int base = beg; base < end; base += 64) {
        const int cnt = min(64, end - base);
        int2 er = make_int2(0, 0);
        if (base + lane < end) er = edges[base + lane];
        int j = 0;
        for (; j + 4 <= cnt; j += 4) {
            const int   s0 = __shfl(er.x, j + 0), s1 = __shfl(er.x, j + 1);
            const int   s2 = __shfl(er.x, j + 2), s3 = __shfl(er.x, j + 3);
            const float w0 = __int_as_float(__shfl(er.y, j + 0));
            const float w1 = __int_as_float(__shfl(er.y, j + 1));
            const float w2 = __int_as_float(__shfl(er.y, j + 2));
            const float w3 = __int_as_float(__shfl(er.y, j + 3));
            const float v0 = bf2f(h2[(size_t)s0 * D_OUT + col]);
            const float v1 = bf2f(h2[(size_t)s1 * D_OUT + col]);
            const float v2 = bf2f(h2[(size_t)s2 * D_OUT + col]);
            const float v3 = bf2f(h2[(size_t)s3 * D_OUT + col]);
            acc += w0 * v0; acc += w1 * v1; acc += w2 * v2; acc += w3 * v3;
        }
        for (; j < cnt; ++j) {
            const int   s0 = __shfl(er.x, j);
            const float w0 = __int_as_float(__shfl(er.y, j));
            acc += w0 * bf2f(h2[(size_t)s0 * D_OUT + col]);
        }
    }
    const float v = (lane < D_OUT) ? acc : -INFINITY;
    float m = v;
#pragma unroll
    for (int o = 32; o > 0; o >>= 1) m = fmaxf(m, __shfl_xor(m, o, 64));
    float s = (lane < D_OUT) ? __expf(v - m) : 0.f;
#pragma unroll
    for (int o = 32; o > 0; o >>= 1) s += __shfl_xor(s, o, 64);
    if (lane < D_OUT) out[(size_t)n * D_OUT + lane] = v - m - __logf(s);
}

// ===========================================================================
extern "C" void kernel_launch(void* const* d_in, const int* in_sizes, int n_in,
                              void* d_out, int out_size, void* d_ws, size_t ws_size,
                              hipStream_t stream) {
    const float* x   = (const float*)d_in[0];
    const int*   ei  = (const int*)d_in[1];
    const float* wm  = (const float*)d_in[2];
    const float* W1  = (const float*)d_in[3];
    const float* b1  = (const float*)d_in[4];
    const float* W2  = (const float*)d_in[5];
    const float* b2  = (const float*)d_in[6];

    const int N = in_sizes[0] / D_IN;   // 50000
    const int E = in_sizes[2];          // 800000
    const int* srcIdx = ei;
    const int* dstIdx = ei + E;

    // workspace layout (16B-aligned blocks first)
    unsigned short* w1T    = (unsigned short*)d_ws;                  // 64 KiB
    unsigned short* h1bf   = w1T + (size_t)D_HID * D_IN;             // N*64 bf16
    unsigned short* agg1bf = h1bf + (size_t)N * D_HID;               // N*64 bf16
    int2*  edges           = (int2*)(agg1bf + (size_t)N * D_HID);    // E int2
    int*   row_start       = (int*)(edges + E);                      // N+1
    int*   cursor          = row_start + (N + 1);                    // N
    int*   counts          = cursor + N;                             // N
    int*   blockSums       = counts + N;                             // <=256
    unsigned short* h2bf   = h1bf;                                   // reuse
    float* out             = (float*)d_out;

    const int NB = (N + 255) / 256;  // 196

    // ---- CSR build (XCD-local hist + scatter); own zero kernel (r6: runtime
    // fillBufferAligned was 57 us/launch for this 200 KB fill)
    zero_counts<<<NB, 256, 0, stream>>>(counts, N);
    hist_xcd<<<2048, 256, 0, stream>>>(dstIdx, counts, E, N);
    scan1_kernel<<<NB, 256, 0, stream>>>(counts, row_start, blockSums, N);
    scan2_kernel<<<1, 256, 0, stream>>>(blockSums, NB);
    scan3_kernel<<<NB, 256, 0, stream>>>(counts, row_start, blockSums, cursor, N);
    scatter_xcd<<<2048, 256, 0, stream>>>(srcIdx, dstIdx, wm, cursor, edges, E, N);

    // ---- network
    prep_w1<<<(D_IN * D_HID + 255) / 256, 256, 0, stream>>>(W1, w1T);
    gemm1_mfma<<<(N + 63) / 64, 256, 0, stream>>>(x, w1T, b1, h1bf, N);
    agg_csr_hid<<<(N * 64 + 255) / 256, 256, 0, stream>>>(h1bf, edges, row_start, agg1bf, N);
    gemm2_kernel<<<2048, 256, 0, stream>>>(agg1bf, W2, b2, h2bf, N);
    agg_csr_out_lsm<<<(N * 64 + 255) / 256, 256, 0, stream>>>(h2bf, edges, row_start, out, N);
}